// Round 13
// baseline (326.084 us; speedup 1.0000x reference)
//
#include <hip/hip_runtime.h>
#include <hip/hip_bf16.h>

// Problem dims (fixed by reference)
#define BATCH 128
#define PIX   196
#define EDIM  2048
#define DDIM  512
#define ADIM  512
#define MTOT  (BATCH*PIX)   // 25088
#define BK    32
#define NK    (EDIM/BK)     // 64 K-tiles

typedef __attribute__((ext_vector_type(8))) short short8;
typedef __attribute__((ext_vector_type(4))) float f32x4;

__device__ __forceinline__ unsigned short f2bf(float f) {
    union { float f; unsigned int u; } c; c.f = f;
    unsigned int u = c.u;
    u += 0x7fffu + ((u >> 16) & 1u);   // round-to-nearest-even
    return (unsigned short)(u >> 16);
}

// HW cvt (compiler emits v_cvt_pk_bf16_f32; RNE, matches f2bf)
__device__ __forceinline__ short8 cvt8(float4 a, float4 b) {
    short8 v;
    v[0] = (short)__bfloat16_as_ushort(__float2bfloat16(a.x));
    v[1] = (short)__bfloat16_as_ushort(__float2bfloat16(a.y));
    v[2] = (short)__bfloat16_as_ushort(__float2bfloat16(a.z));
    v[3] = (short)__bfloat16_as_ushort(__float2bfloat16(a.w));
    v[4] = (short)__bfloat16_as_ushort(__float2bfloat16(b.x));
    v[5] = (short)__bfloat16_as_ushort(__float2bfloat16(b.y));
    v[6] = (short)__bfloat16_as_ushort(__float2bfloat16(b.z));
    v[7] = (short)__bfloat16_as_ushort(__float2bfloat16(b.w));
    return v;
}

#define MFMA16(a, b, c) __builtin_amdgcn_mfma_f32_16x16x32_bf16(a, b, c, 0, 0, 0)

// ---------------------------------------------------------------------------
// Kernel 0: pack W_enc [K=2048][A=512] fp32 -> per-(kt,nb) 4KB frag blocks.
// ushort idx (kt*8+nb)*2048 + j*512 + l*8 + d  holds bf16 of
//   W_enc[kt*32 + (l>>4)*8 + d][nb*64 + j*16 + (l&15)]
// gemm lane l reads frag j as one dwordx4 at short8-index
//   (kt*8+nb)*256 + j*64 + l  -> contiguous 4KB per (kt,nb): pure L2 stream.
// ---------------------------------------------------------------------------
__global__ __launch_bounds__(256) void pack_wenc(const float* __restrict__ Wenc,
                                                 unsigned short* __restrict__ WTp) {
    __shared__ float f[32 * ADIM];   // 64 KB: rows k=kt*32..+31
    const int kt = blockIdx.x;       // 64 blocks
    const int tid = threadIdx.x;
    const float4* src = (const float4*)(Wenc + (size_t)kt * 32 * ADIM);
    float4* dst = (float4*)f;
    #pragma unroll
    for (int i = 0; i < 16; ++i)
        dst[tid + i * 256] = src[tid + i * 256];
    __syncthreads();
    #pragma unroll
    for (int cc = 0; cc < 8; ++cc) {
        int s   = tid + cc * 256;        // 0..2047
        int nb  = s >> 8;
        int j   = (s >> 6) & 3;
        int kc  = (s >> 4) & 3;
        int cf  = s & 15;
        int n   = nb * 64 + j * 16 + cf;
        short8 v;
        #pragma unroll
        for (int d = 0; d < 8; ++d)
            v[d] = (short)f2bf(f[(kc * 8 + d) * ADIM + n]);
        *(short8*)(WTp + (size_t)(kt * 8 + nb) * 2048 + j * 512
                       + (kc * 16 + cf) * 8) = v;
    }
}

// ---------------------------------------------------------------------------
// Kernel 1: bias[b][a] = sum_d dec[b][d]*Wdec[d][a] + b_dec[a] + b_enc[a]
// ---------------------------------------------------------------------------
__global__ __launch_bounds__(256) void bias_kernel(const float* __restrict__ dec,
                                                   const float* __restrict__ Wdec,
                                                   const float* __restrict__ b_enc,
                                                   const float* __restrict__ b_dec,
                                                   float* __restrict__ bias) {
    __shared__ float ds[4 * DDIM];
    const int b0 = blockIdx.x * 4;
    for (int i = threadIdx.x; i < 4 * DDIM; i += 256)
        ds[i] = dec[(size_t)b0 * DDIM + i];
    __syncthreads();
    const int a0 = threadIdx.x * 2;
    float acc0[4] = {0.f, 0.f, 0.f, 0.f};
    float acc1[4] = {0.f, 0.f, 0.f, 0.f};
    for (int d = 0; d < DDIM; d++) {
        float2 w = *(const float2*)&Wdec[(size_t)d * ADIM + a0];
        #pragma unroll
        for (int bi = 0; bi < 4; bi++) {
            float dv = ds[bi * DDIM + d];
            acc0[bi] += dv * w.x;
            acc1[bi] += dv * w.y;
        }
    }
    float be0 = b_enc[a0] + b_dec[a0];
    float be1 = b_enc[a0 + 1] + b_dec[a0 + 1];
    #pragma unroll
    for (int bi = 0; bi < 4; bi++) {
        bias[(size_t)(b0 + bi) * ADIM + a0]     = acc0[bi] + be0;
        bias[(size_t)(b0 + bi) * ADIM + a0 + 1] = acc1[bi] + be1;
    }
}

// ---------------------------------------------------------------------------
// Kernel 2: fused att1 GEMM + relu + dot(W_full) -> att_part[nb][m]
// NO LDS. NO BARRIERS. NO INLINE ASM. 784 blocks (98 M-panels x 8 col-blocks,
// XCD-swizzled so a panel's 8 col-twins share one XCD's L2). 4 waves/block,
// each wave owns a 64x64 output tile (acc[4][4]): A fp32 direct global->reg
// (16-row x 128B fully-consumed segments) + hw cvt; B direct global->reg from
// 4KB contiguous L2-hot frag blocks. Waves fully independent; compiler does
// all scheduling (counted waitcnts, load hoisting across unrolled iters).
// ---------------------------------------------------------------------------
__global__ __launch_bounds__(256, 2) void gemm_att(const float* __restrict__ enc,
                                                   const unsigned short* __restrict__ WTp,
                                                   const float* __restrict__ bias,
                                                   const float* __restrict__ Wfull,
                                                   float* __restrict__ att_part) {
    const int tid  = threadIdx.x;
    const int lane = tid & 63;
    const int wm   = tid >> 6;          // 0..3: M quarter (64 rows)
    const int cif  = lane & 15;
    const int rgrp = lane >> 4;

    // Bijective XCD swizzle: panel g's 8 nb-twins all land on XCD g%8.
    const int bid = blockIdx.x;
    int g, nb;
    if (bid < 768) { g = (bid >> 6) * 8 + (bid & 7); nb = (bid >> 3) & 7; }
    else           { int r2 = bid - 768; g = 96 + (r2 >> 3); nb = r2 & 7; }
    const int m0 = g * 256;

    // A: lane covers rows m0 + wm*64 + i*16 + cif (i=0..3), k-window rgrp*8.
    // Quarter-wave = 16 rows x 32B, full wave covers 16 rows x 128B: every
    // touched 128B line fully consumed within the instruction.
    const float* pA0 = enc + (size_t)(m0 + wm * 64 +  0 + cif) * EDIM + rgrp * 8;
    const float* pA1 = pA0 + (size_t)16 * EDIM;
    const float* pA2 = pA0 + (size_t)32 * EDIM;
    const float* pA3 = pA0 + (size_t)48 * EDIM;

    // B: lane's frag-j dwordx4 at short8-index (kt*8+nb)*256 + j*64 + lane.
    const short8* pB = (const short8*)WTp + (size_t)nb * 256 + lane;

    f32x4 acc[4][4] = {};

    #pragma unroll 4
    for (int kt = 0; kt < NK; ++kt) {
        const int ko = kt * BK;
        short8 a0 = cvt8(*(const float4*)(pA0 + ko), *(const float4*)(pA0 + ko + 4));
        short8 a1 = cvt8(*(const float4*)(pA1 + ko), *(const float4*)(pA1 + ko + 4));
        short8 a2 = cvt8(*(const float4*)(pA2 + ko), *(const float4*)(pA2 + ko + 4));
        short8 a3 = cvt8(*(const float4*)(pA3 + ko), *(const float4*)(pA3 + ko + 4));
        const short8* pb = pB + (size_t)kt * 2048;
        short8 b0 = pb[0], b1 = pb[64], b2 = pb[128], b3 = pb[192];

        acc[0][0] = MFMA16(a0, b0, acc[0][0]);
        acc[0][1] = MFMA16(a0, b1, acc[0][1]);
        acc[0][2] = MFMA16(a0, b2, acc[0][2]);
        acc[0][3] = MFMA16(a0, b3, acc[0][3]);
        acc[1][0] = MFMA16(a1, b0, acc[1][0]);
        acc[1][1] = MFMA16(a1, b1, acc[1][1]);
        acc[1][2] = MFMA16(a1, b2, acc[1][2]);
        acc[1][3] = MFMA16(a1, b3, acc[1][3]);
        acc[2][0] = MFMA16(a2, b0, acc[2][0]);
        acc[2][1] = MFMA16(a2, b1, acc[2][1]);
        acc[2][2] = MFMA16(a2, b2, acc[2][2]);
        acc[2][3] = MFMA16(a2, b3, acc[2][3]);
        acc[3][0] = MFMA16(a3, b0, acc[3][0]);
        acc[3][1] = MFMA16(a3, b1, acc[3][1]);
        acc[3][2] = MFMA16(a3, b2, acc[3][2]);
        acc[3][3] = MFMA16(a3, b3, acc[3][3]);
    }

    // ---- epilogue: relu(acc + bias) . Wfull over this 64-col block ----
    // Wave owns rows [m0+wm*64, +64): spans at most one batch boundary.
    const int wbase = m0 + wm * 64;
    const int bfw = wbase / PIX;
    const int thr = (bfw + 1) * PIX;
    const int bfc = (bfw + 1 < BATCH) ? bfw + 1 : BATCH - 1;
    float wf[4], bs0[4], bs1[4];
    #pragma unroll
    for (int j = 0; j < 4; ++j) {
        int aj = nb * 64 + j * 16 + cif;
        wf[j]  = Wfull[aj];
        bs0[j] = bias[(size_t)bfw * ADIM + aj];
        bs1[j] = bias[(size_t)bfc * ADIM + aj];
    }
    #pragma unroll
    for (int i = 0; i < 4; ++i) {
        #pragma unroll
        for (int rr = 0; rr < 4; ++rr) {
            int m = wbase + i * 16 + rgrp * 4 + rr;
            bool sec = (m >= thr);
            float s = 0.f;
            #pragma unroll
            for (int j = 0; j < 4; ++j) {
                float v = acc[i][j][rr] + (sec ? bs1[j] : bs0[j]);
                s += fmaxf(v, 0.f) * wf[j];
            }
            s += __shfl_xor(s, 1);
            s += __shfl_xor(s, 2);
            s += __shfl_xor(s, 4);
            s += __shfl_xor(s, 8);
            if (cif == 0) att_part[(size_t)nb * MTOT + m] = s;
        }
    }
}

// ---------------------------------------------------------------------------
// Kernel 3: softmax over p; att = sum of 8 col-block partials (b_full cancels)
// ---------------------------------------------------------------------------
__global__ __launch_bounds__(256) void softmax_kernel(const float* __restrict__ att_part,
                                                      float* __restrict__ alpha) {
    const int b = blockIdx.x;
    const int tid = threadIdx.x;
    const int lane = tid & 63, wid = tid >> 6;
    __shared__ float wred[4];

    float x = -1e30f;
    if (tid < PIX) {
        size_t m = (size_t)b * PIX + tid;
        x = 0.f;
        #pragma unroll
        for (int q = 0; q < 8; ++q)
            x += att_part[(size_t)q * MTOT + m];
    }
    float mx = x;
    #pragma unroll
    for (int off = 32; off >= 1; off >>= 1) mx = fmaxf(mx, __shfl_xor(mx, off));
    if (lane == 0) wred[wid] = mx;
    __syncthreads();
    float gm = fmaxf(fmaxf(wred[0], wred[1]), fmaxf(wred[2], wred[3]));
    __syncthreads();

    float e = (tid < PIX) ? __expf(x - gm) : 0.f;
    float s = e;
    #pragma unroll
    for (int off = 32; off >= 1; off >>= 1) s += __shfl_xor(s, off);
    if (lane == 0) wred[wid] = s;
    __syncthreads();
    float gs = wred[0] + wred[1] + wred[2] + wred[3];

    if (tid < PIX) alpha[(size_t)b * PIX + tid] = e / gs;
}

// ---------------------------------------------------------------------------
// Kernel 4: out[b][e] = sum_p enc[b][p][e] * alpha[b][p]
// ---------------------------------------------------------------------------
__global__ __launch_bounds__(128) void weighted_kernel(const float* __restrict__ enc,
                                                       const float* __restrict__ alpha,
                                                       float* __restrict__ out) {
    const int b = blockIdx.x >> 2;
    const int q = blockIdx.x & 3;
    const int tid = threadIdx.x;
    __shared__ float al[PIX];
    for (int i = tid; i < PIX; i += 128) al[i] = alpha[(size_t)b * PIX + i];
    __syncthreads();

    const int e = q * 512 + tid * 4;
    const float4* src = (const float4*)(enc + (size_t)b * PIX * EDIM + e);
    float ax = 0.f, ay = 0.f, az = 0.f, aw = 0.f;
    #pragma unroll 4
    for (int p = 0; p < PIX; p++) {
        float av = al[p];
        float4 v = src[(size_t)p * (EDIM / 4)];
        ax += av * v.x; ay += av * v.y; az += av * v.z; aw += av * v.w;
    }
    float4 o; o.x = ax; o.y = ay; o.z = az; o.w = aw;
    *(float4*)&out[(size_t)b * EDIM + e] = o;
}

// ---------------------------------------------------------------------------
extern "C" void kernel_launch(void* const* d_in, const int* in_sizes, int n_in,
                              void* d_out, int out_size, void* d_ws, size_t ws_size,
                              hipStream_t stream) {
    const float* enc   = (const float*)d_in[0];   // [128,196,2048]
    const float* dec   = (const float*)d_in[1];   // [128,512]
    const float* Wenc  = (const float*)d_in[2];   // [2048,512]
    const float* benc  = (const float*)d_in[3];   // [512]
    const float* Wdec  = (const float*)d_in[4];   // [512,512]
    const float* bdec  = (const float*)d_in[5];   // [512]
    const float* Wfull = (const float*)d_in[6];   // [512]
    // d_in[7] = b_full: constant shift, cancels in softmax

    float* out_awe   = (float*)d_out;                       // [128,2048]
    float* out_alpha = (float*)d_out + BATCH * EDIM;        // [128,196]

    char* ws = (char*)d_ws;
    unsigned short* WTp = (unsigned short*)ws;                      // 2 MB packed frags
    float* bias = (float*)(ws + (size_t)ADIM * EDIM * 2);           // 256 KB [128][512]
    float* att_part = (float*)(ws + (size_t)ADIM * EDIM * 2
                             + (size_t)BATCH * ADIM * 4);           // 8 x 100 KB

    pack_wenc<<<NK, 256, 0, stream>>>(Wenc, WTp);
    bias_kernel<<<BATCH / 4, 256, 0, stream>>>(dec, Wdec, benc, bdec, bias);
    gemm_att<<<784, 256, 0, stream>>>(enc, WTp, bias, Wfull, att_part);
    softmax_kernel<<<BATCH, 256, 0, stream>>>(att_part, out_alpha);
    weighted_kernel<<<BATCH * 4, 128, 0, stream>>>(enc, out_alpha, out_awe);
}

// Round 14
// 177.349 us; speedup vs baseline: 1.8387x; 1.8387x over previous
//
#include <hip/hip_runtime.h>
#include <hip/hip_bf16.h>

// Problem dims (fixed by reference)
#define BATCH 128
#define PIX   196
#define EDIM  2048
#define DDIM  512
#define ADIM  512
#define MTOT  (BATCH*PIX)   // 25088
#define BK    32
#define NK    (EDIM/BK)     // 64 K-tiles
#define BM    128
#define NSLC  4             // 4 N-slices of 128

typedef __attribute__((ext_vector_type(8))) short short8;
typedef __attribute__((ext_vector_type(4))) float f32x4;

__device__ __forceinline__ unsigned short f2bf(float f) {
    union { float f; unsigned int u; } c; c.f = f;
    unsigned int u = c.u;
    u += 0x7fffu + ((u >> 16) & 1u);   // round-to-nearest-even
    return (unsigned short)(u >> 16);
}

// HW cvt (v_cvt_pk_bf16_f32; RNE, matches f2bf)
__device__ __forceinline__ short8 cvt8(float4 a, float4 b) {
    short8 v;
    v[0] = (short)__bfloat16_as_ushort(__float2bfloat16(a.x));
    v[1] = (short)__bfloat16_as_ushort(__float2bfloat16(a.y));
    v[2] = (short)__bfloat16_as_ushort(__float2bfloat16(a.z));
    v[3] = (short)__bfloat16_as_ushort(__float2bfloat16(a.w));
    v[4] = (short)__bfloat16_as_ushort(__float2bfloat16(b.x));
    v[5] = (short)__bfloat16_as_ushort(__float2bfloat16(b.y));
    v[6] = (short)__bfloat16_as_ushort(__float2bfloat16(b.z));
    v[7] = (short)__bfloat16_as_ushort(__float2bfloat16(b.w));
    return v;
}

#define GLOAD16(gp, lp) __builtin_amdgcn_global_load_lds( \
    (const __attribute__((address_space(1))) void*)(gp),  \
    (__attribute__((address_space(3))) void*)(lp), 16, 0, 0)

#define MFMA16(a, b, c) __builtin_amdgcn_mfma_f32_16x16x32_bf16(a, b, c, 0, 0, 0)

// ---------------------------------------------------------------------------
// Kernel 0: pack W_enc [K=2048][A=512] fp32 -> per-(kt,ns) 8KB images, bf16.
// Image (kt,ns) = 4096 ushorts; slot layout: chunk=0..7 (512 ushort each),
// lane l=0..63, d=0..7:
//   WTp[(kt*4+ns)*4096 + chunk*512 + l*8 + d] =
//     bf16( W_enc[kt*32 + (l>>4)*8 + d][ns*128 + chunk*16 + (l&15)] )
// gemm: gload_lds copies chunks linearly; frag j read at
//   (wn*4+j)*1024 + lane*16 bytes  (lane-linear, conflict-free).
// ---------------------------------------------------------------------------
__global__ __launch_bounds__(256) void pack_wenc(const float* __restrict__ Wenc,
                                                 unsigned short* __restrict__ WTp) {
    __shared__ float f[32 * ADIM];   // 64 KB: rows k=kt*32..+31
    const int kt = blockIdx.x;       // 64 blocks
    const int tid = threadIdx.x;
    const float4* src = (const float4*)(Wenc + (size_t)kt * 32 * ADIM);
    float4* dst = (float4*)f;
    #pragma unroll
    for (int i = 0; i < 16; ++i)
        dst[tid + i * 256] = src[tid + i * 256];
    __syncthreads();
    #pragma unroll
    for (int cc = 0; cc < 8; ++cc) {
        int s     = tid + cc * 256;      // 0..2047 slots (8 ushort each)
        int ns    = s >> 9;              // 0..3
        int chunk = (s >> 6) & 7;        // 0..7
        int l     = s & 63;
        int n     = ns * 128 + chunk * 16 + (l & 15);
        int k0    = (l >> 4) * 8;
        short8 v;
        #pragma unroll
        for (int d = 0; d < 8; ++d)
            v[d] = (short)f2bf(f[(k0 + d) * ADIM + n]);
        *(short8*)(WTp + (size_t)kt * 16384 + (size_t)ns * 4096
                       + chunk * 512 + l * 8) = v;
    }
}

// ---------------------------------------------------------------------------
// Kernel 1: bias[b][a] = sum_d dec[b][d]*Wdec[d][a] + b_dec[a] + b_enc[a]
// ---------------------------------------------------------------------------
__global__ __launch_bounds__(256) void bias_kernel(const float* __restrict__ dec,
                                                   const float* __restrict__ Wdec,
                                                   const float* __restrict__ b_enc,
                                                   const float* __restrict__ b_dec,
                                                   float* __restrict__ bias) {
    __shared__ float ds[4 * DDIM];
    const int b0 = blockIdx.x * 4;
    for (int i = threadIdx.x; i < 4 * DDIM; i += 256)
        ds[i] = dec[(size_t)b0 * DDIM + i];
    __syncthreads();
    const int a0 = threadIdx.x * 2;
    float acc0[4] = {0.f, 0.f, 0.f, 0.f};
    float acc1[4] = {0.f, 0.f, 0.f, 0.f};
    for (int d = 0; d < DDIM; d++) {
        float2 w = *(const float2*)&Wdec[(size_t)d * ADIM + a0];
        #pragma unroll
        for (int bi = 0; bi < 4; bi++) {
            float dv = ds[bi * DDIM + d];
            acc0[bi] += dv * w.x;
            acc1[bi] += dv * w.y;
        }
    }
    float be0 = b_enc[a0] + b_dec[a0];
    float be1 = b_enc[a0 + 1] + b_dec[a0 + 1];
    #pragma unroll
    for (int bi = 0; bi < 4; bi++) {
        bias[(size_t)(b0 + bi) * ADIM + a0]     = acc0[bi] + be0;
        bias[(size_t)(b0 + bi) * ADIM + a0 + 1] = acc1[bi] + be1;
    }
}

// ---------------------------------------------------------------------------
// Kernel 2: fused att1 GEMM + relu + dot(W_full) -> att_part[ns][m]
// m97-faithful: 128M x 128N x 32K, 4 waves (2M x 2N), wave tile 64x64,
// acc[4][4] (AGPR). LDS 32 KB (A dbuf 2x8K + B dbuf 2x8K) + VGPR<=128
// (__launch_bounds__(256,4)) -> 16 waves/CU = 4 INDEPENDENT blocks/CU:
// other blocks' MFMA covers each block's barrier drain (m114/m97 mechanism).
// Plain __syncthreads(), ONE barrier/iter, no inline asm, no setprio —
// the compiler's own counted lgkmcnt + drain-at-barrier is the m97-proven
// schedule. Grid 784 = 196 panels x 4 slices, XCD-swizzled (panel's 4
// twins share an XCD -> A-panel L2 reuse, r8-proven).
// ---------------------------------------------------------------------------
__global__ __launch_bounds__(256, 4) void gemm_att(const float* __restrict__ enc,
                                                   const unsigned short* __restrict__ WTp,
                                                   const float* __restrict__ bias,
                                                   const float* __restrict__ Wfull,
                                                   float* __restrict__ att_part) {
    __shared__ __align__(16) char ldsA[2][8192];
    __shared__ __align__(16) char ldsB[2][8192];

    const int tid  = threadIdx.x;
    const int lane = tid & 63;
    const int wid  = tid >> 6;          // 0..3
    const int wm   = wid >> 1;          // 0..1 (M half: 64 rows)
    const int wn   = wid & 1;           // 0..1 (N half: 64 cols)
    const int cif  = lane & 15;
    const int rgrp = lane >> 4;

    // XCD swizzle (bijective for 784 = 24*32 + 16): panel g's 4 ns-twins
    // are 8 raw slots apart -> same XCD.
    const int raw = blockIdx.x;
    int g, ns;
    if (raw < 768) { g = (raw >> 5) * 8 + (raw & 7); ns = (raw >> 3) & 3; }
    else           { int r2 = raw - 768; g = 192 + (r2 >> 2); ns = r2 & 3; }
    const int m0 = g * BM;

    // A: thread t -> row r=t>>1, k-half h=t&1 (16 floats of the 32-K tile).
    const int r = tid >> 1, h = tid & 1;
    const float* pA = enc + (size_t)(m0 + r) * EDIM + h * 16;
    // two ds_write_b128 at chunk (r>>4), lane-slots h*32+(r&15), +16:
    const unsigned aWoff = (unsigned)((r >> 4) * 1024 + (h * 32 + (r & 15)) * 16);

    // B: wave wid copies image chunks wid*2, wid*2+1 (1 KB each).
    const unsigned short* pB = WTp + (size_t)ns * 4096 + (size_t)(wid * 2) * 512
                             + (size_t)lane * 8;            // + kt*16384
    const unsigned bgOff = (unsigned)(wid * 2048);

    char* aR = ldsA[0]; char* aW = ldsA[1];
    char* bR = ldsB[0]; char* bW = ldsB[1];

    f32x4 acc[4][4] = {};

    // ---- prologue: stage tile 0 into aR/bR ----
    GLOAD16(pB,       bR + bgOff);
    GLOAD16(pB + 512, bR + bgOff + 1024);
    {
        float4 t0 = *(const float4*)pA;
        float4 t1 = *(const float4*)(pA + 4);
        float4 t2 = *(const float4*)(pA + 8);
        float4 t3 = *(const float4*)(pA + 12);
        *(short8*)(aR + aWoff)       = cvt8(t0, t1);
        *(short8*)(aR + aWoff + 256) = cvt8(t2, t3);
    }
    __syncthreads();

    // ---- main loop: kt = 0 .. NK-2: stage kt+1, compute kt, 1 barrier ----
    for (int kt = 0; kt < NK - 1; ++kt) {
        // stage B(kt+1)
        const unsigned short* pb = pB + (size_t)(kt + 1) * 16384;
        GLOAD16(pb,       bW + bgOff);
        GLOAD16(pb + 512, bW + bgOff + 1024);
        // stage A(kt+1): global->reg->cvt->ds_write (to the write buffer)
        {
            const float* pa = pA + (kt + 1) * BK;
            float4 t0 = *(const float4*)pa;
            float4 t1 = *(const float4*)(pa + 4);
            float4 t2 = *(const float4*)(pa + 8);
            float4 t3 = *(const float4*)(pa + 12);
            *(short8*)(aW + aWoff)       = cvt8(t0, t1);
            *(short8*)(aW + aWoff + 256) = cvt8(t2, t3);
        }
        // compute kt
        {
            short8 a[4], b[4];
            #pragma unroll
            for (int i = 0; i < 4; ++i)
                a[i] = *(const short8*)(aR + (wm * 4 + i) * 1024 + lane * 16);
            #pragma unroll
            for (int j = 0; j < 4; ++j)
                b[j] = *(const short8*)(bR + (wn * 4 + j) * 1024 + lane * 16);
            #pragma unroll
            for (int i = 0; i < 4; ++i)
                #pragma unroll
                for (int j = 0; j < 4; ++j)
                    acc[i][j] = MFMA16(a[i], b[j], acc[i][j]);
        }
        __syncthreads();
        { char* t = aR; aR = aW; aW = t; }
        { char* t = bR; bR = bW; bW = t; }
    }
    // ---- final compute kt = NK-1 ----
    {
        short8 a[4], b[4];
        #pragma unroll
        for (int i = 0; i < 4; ++i)
            a[i] = *(const short8*)(aR + (wm * 4 + i) * 1024 + lane * 16);
        #pragma unroll
        for (int j = 0; j < 4; ++j)
            b[j] = *(const short8*)(bR + (wn * 4 + j) * 1024 + lane * 16);
        #pragma unroll
        for (int i = 0; i < 4; ++i)
            #pragma unroll
            for (int j = 0; j < 4; ++j)
                acc[i][j] = MFMA16(a[i], b[j], acc[i][j]);
    }
    __syncthreads();   // before aliasing ldsA as reduction buffer

    // ---- epilogue: relu(acc + bias) . Wfull over this slice's 128 cols ----
    float* red = (float*)ldsA;   // [2][128] floats (aliases ldsA)
    const int bf  = m0 / PIX;
    const int thr = (bf + 1) * PIX;
    const int bfc = (bf + 1 < BATCH) ? bf + 1 : BATCH - 1;
    float wf[4], bs0[4], bs1[4];
    #pragma unroll
    for (int j = 0; j < 4; ++j) {
        int aj = ns * 128 + wn * 64 + j * 16 + cif;
        wf[j]  = Wfull[aj];
        bs0[j] = bias[(size_t)bf  * ADIM + aj];
        bs1[j] = bias[(size_t)bfc * ADIM + aj];
    }
    #pragma unroll
    for (int i = 0; i < 4; ++i) {
        #pragma unroll
        for (int rr = 0; rr < 4; ++rr) {
            int ml = wm * 64 + i * 16 + rgrp * 4 + rr;
            int m  = m0 + ml;
            bool sec = (m >= thr);
            float s = 0.f;
            #pragma unroll
            for (int j = 0; j < 4; ++j) {
                float v = acc[i][j][rr] + (sec ? bs1[j] : bs0[j]);
                s += fmaxf(v, 0.f) * wf[j];
            }
            s += __shfl_xor(s, 1);
            s += __shfl_xor(s, 2);
            s += __shfl_xor(s, 4);
            s += __shfl_xor(s, 8);
            if (cif == 0) red[wn * 128 + ml] = s;
        }
    }
    __syncthreads();
    if (tid < BM)
        att_part[(size_t)ns * MTOT + m0 + tid] = red[tid] + red[128 + tid];
}

// ---------------------------------------------------------------------------
// Kernel 3: softmax over p; att = sum of 4 N-slice partials (b_full cancels)
// ---------------------------------------------------------------------------
__global__ __launch_bounds__(256) void softmax_kernel(const float* __restrict__ att_part,
                                                      float* __restrict__ alpha) {
    const int b = blockIdx.x;
    const int tid = threadIdx.x;
    const int lane = tid & 63, wid = tid >> 6;
    __shared__ float wred[4];

    float x = -1e30f;
    if (tid < PIX) {
        size_t m = (size_t)b * PIX + tid;
        x = att_part[m] + att_part[MTOT + m] + att_part[2 * MTOT + m]
          + att_part[3 * MTOT + m];
    }
    float mx = x;
    #pragma unroll
    for (int off = 32; off >= 1; off >>= 1) mx = fmaxf(mx, __shfl_xor(mx, off));
    if (lane == 0) wred[wid] = mx;
    __syncthreads();
    float gm = fmaxf(fmaxf(wred[0], wred[1]), fmaxf(wred[2], wred[3]));
    __syncthreads();

    float e = (tid < PIX) ? __expf(x - gm) : 0.f;
    float s = e;
    #pragma unroll
    for (int off = 32; off >= 1; off >>= 1) s += __shfl_xor(s, off);
    if (lane == 0) wred[wid] = s;
    __syncthreads();
    float gs = wred[0] + wred[1] + wred[2] + wred[3];

    if (tid < PIX) alpha[(size_t)b * PIX + tid] = e / gs;
}

// ---------------------------------------------------------------------------
// Kernel 4: out[b][e] = sum_p enc[b][p][e] * alpha[b][p]
// ---------------------------------------------------------------------------
__global__ __launch_bounds__(128) void weighted_kernel(const float* __restrict__ enc,
                                                       const float* __restrict__ alpha,
                                                       float* __restrict__ out) {
    const int b = blockIdx.x >> 2;
    const int q = blockIdx.x & 3;
    const int tid = threadIdx.x;
    __shared__ float al[PIX];
    for (int i = tid; i < PIX; i += 128) al[i] = alpha[(size_t)b * PIX + i];
    __syncthreads();

    const int e = q * 512 + tid * 4;
    const float4* src = (const float4*)(enc + (size_t)b * PIX * EDIM + e);
    float ax = 0.f, ay = 0.f, az = 0.f, aw = 0.f;
    #pragma unroll 4
    for (int p = 0; p < PIX; p++) {
        float av = al[p];
        float4 v = src[(size_t)p * (EDIM / 4)];
        ax += av * v.x; ay += av * v.y; az += av * v.z; aw += av * v.w;
    }
    float4 o; o.x = ax; o.y = ay; o.z = az; o.w = aw;
    *(float4*)&out[(size_t)b * EDIM + e] = o;
}

// ---------------------------------------------------------------------------
extern "C" void kernel_launch(void* const* d_in, const int* in_sizes, int n_in,
                              void* d_out, int out_size, void* d_ws, size_t ws_size,
                              hipStream_t stream) {
    const float* enc   = (const float*)d_in[0];   // [128,196,2048]
    const float* dec   = (const float*)d_in[1];   // [128,512]
    const float* Wenc  = (const float*)d_in[2];   // [2048,512]
    const float* benc  = (const float*)d_in[3];   // [512]
    const float* Wdec  = (const float*)d_in[4];   // [512,512]
    const float* bdec  = (const float*)d_in[5];   // [512]
    const float* Wfull = (const float*)d_in[6];   // [512]
    // d_in[7] = b_full: constant shift, cancels in softmax

    float* out_awe   = (float*)d_out;                       // [128,2048]
    float* out_alpha = (float*)d_out + BATCH * EDIM;        // [128,196]

    char* ws = (char*)d_ws;
    unsigned short* WTp = (unsigned short*)ws;                      // 2 MB packed images
    float* bias = (float*)(ws + (size_t)ADIM * EDIM * 2);           // 256 KB [128][512]
    float* att_part = (float*)(ws + (size_t)ADIM * EDIM * 2
                             + (size_t)BATCH * ADIM * 4);           // 4 x 100 KB

    pack_wenc<<<NK, 256, 0, stream>>>(Wenc, WTp);
    bias_kernel<<<BATCH / 4, 256, 0, stream>>>(dec, Wdec, benc, bdec, bias);
    gemm_att<<<(MTOT / BM) * NSLC, 256, 0, stream>>>(enc, WTp, bias, Wfull, att_part);
    softmax_kernel<<<BATCH, 256, 0, stream>>>(att_part, out_alpha);
    weighted_kernel<<<BATCH * 4, 128, 0, stream>>>(enc, out_alpha, out_awe);
}

// Round 15
// 173.983 us; speedup vs baseline: 1.8742x; 1.0194x over previous
//
#include <hip/hip_runtime.h>
#include <hip/hip_bf16.h>

// Problem dims (fixed by reference)
#define BATCH 128
#define PIX   196
#define EDIM  2048
#define DDIM  512
#define ADIM  512
#define MTOT  (BATCH*PIX)   // 25088
#define BK    32
#define NK    (EDIM/BK)     // 64 K-tiles
#define BM    128
#define NSLC  4             // 4 N-slices of 128

typedef __attribute__((ext_vector_type(8))) short short8;
typedef __attribute__((ext_vector_type(4))) float f32x4;

__device__ __forceinline__ unsigned short f2bf(float f) {
    union { float f; unsigned int u; } c; c.f = f;
    unsigned int u = c.u;
    u += 0x7fffu + ((u >> 16) & 1u);   // round-to-nearest-even
    return (unsigned short)(u >> 16);
}

// HW cvt (v_cvt_pk_bf16_f32; RNE, matches f2bf)
__device__ __forceinline__ short8 cvt8(float4 a, float4 b) {
    short8 v;
    v[0] = (short)__bfloat16_as_ushort(__float2bfloat16(a.x));
    v[1] = (short)__bfloat16_as_ushort(__float2bfloat16(a.y));
    v[2] = (short)__bfloat16_as_ushort(__float2bfloat16(a.z));
    v[3] = (short)__bfloat16_as_ushort(__float2bfloat16(a.w));
    v[4] = (short)__bfloat16_as_ushort(__float2bfloat16(b.x));
    v[5] = (short)__bfloat16_as_ushort(__float2bfloat16(b.y));
    v[6] = (short)__bfloat16_as_ushort(__float2bfloat16(b.z));
    v[7] = (short)__bfloat16_as_ushort(__float2bfloat16(b.w));
    return v;
}

#define GLOAD16(gp, lp) __builtin_amdgcn_global_load_lds( \
    (const __attribute__((address_space(1))) void*)(gp),  \
    (__attribute__((address_space(3))) void*)(lp), 16, 0, 0)

#define MFMA16(a, b, c) __builtin_amdgcn_mfma_f32_16x16x32_bf16(a, b, c, 0, 0, 0)

// ---------------------------------------------------------------------------
// Kernel 0: pack W_enc [K=2048][A=512] fp32 -> per-(kt,ns) 8KB images, bf16.
// Image (kt,ns) = 4096 ushorts; slot layout: chunk=0..7 (512 ushort each),
// lane l=0..63, d=0..7:
//   WTp[(kt*4+ns)*4096 + chunk*512 + l*8 + d] =
//     bf16( W_enc[kt*32 + (l>>4)*8 + d][ns*128 + chunk*16 + (l&15)] )
// gemm: gload_lds copies chunks linearly; frag j read at
//   (wn*4+j)*1024 + lane*16 bytes  (lane-linear, conflict-free).
// ---------------------------------------------------------------------------
__global__ __launch_bounds__(256) void pack_wenc(const float* __restrict__ Wenc,
                                                 unsigned short* __restrict__ WTp) {
    __shared__ float f[32 * ADIM];   // 64 KB: rows k=kt*32..+31
    const int kt = blockIdx.x;       // 64 blocks
    const int tid = threadIdx.x;
    const float4* src = (const float4*)(Wenc + (size_t)kt * 32 * ADIM);
    float4* dst = (float4*)f;
    #pragma unroll
    for (int i = 0; i < 16; ++i)
        dst[tid + i * 256] = src[tid + i * 256];
    __syncthreads();
    #pragma unroll
    for (int cc = 0; cc < 8; ++cc) {
        int s     = tid + cc * 256;      // 0..2047 slots (8 ushort each)
        int ns    = s >> 9;              // 0..3
        int chunk = (s >> 6) & 7;        // 0..7
        int l     = s & 63;
        int n     = ns * 128 + chunk * 16 + (l & 15);
        int k0    = (l >> 4) * 8;
        short8 v;
        #pragma unroll
        for (int d = 0; d < 8; ++d)
            v[d] = (short)f2bf(f[(k0 + d) * ADIM + n]);
        *(short8*)(WTp + (size_t)kt * 16384 + (size_t)ns * 4096
                       + chunk * 512 + l * 8) = v;
    }
}

// ---------------------------------------------------------------------------
// Kernel 1: bias[b][a] = sum_d dec[b][d]*Wdec[d][a] + b_dec[a] + b_enc[a]
// ---------------------------------------------------------------------------
__global__ __launch_bounds__(256) void bias_kernel(const float* __restrict__ dec,
                                                   const float* __restrict__ Wdec,
                                                   const float* __restrict__ b_enc,
                                                   const float* __restrict__ b_dec,
                                                   float* __restrict__ bias) {
    __shared__ float ds[4 * DDIM];
    const int b0 = blockIdx.x * 4;
    for (int i = threadIdx.x; i < 4 * DDIM; i += 256)
        ds[i] = dec[(size_t)b0 * DDIM + i];
    __syncthreads();
    const int a0 = threadIdx.x * 2;
    float acc0[4] = {0.f, 0.f, 0.f, 0.f};
    float acc1[4] = {0.f, 0.f, 0.f, 0.f};
    for (int d = 0; d < DDIM; d++) {
        float2 w = *(const float2*)&Wdec[(size_t)d * ADIM + a0];
        #pragma unroll
        for (int bi = 0; bi < 4; bi++) {
            float dv = ds[bi * DDIM + d];
            acc0[bi] += dv * w.x;
            acc1[bi] += dv * w.y;
        }
    }
    float be0 = b_enc[a0] + b_dec[a0];
    float be1 = b_enc[a0 + 1] + b_dec[a0 + 1];
    #pragma unroll
    for (int bi = 0; bi < 4; bi++) {
        bias[(size_t)(b0 + bi) * ADIM + a0]     = acc0[bi] + be0;
        bias[(size_t)(b0 + bi) * ADIM + a0 + 1] = acc1[bi] + be1;
    }
}

// ---------------------------------------------------------------------------
// Kernel 2: fused att1 GEMM + relu + dot(W_full) -> att_part[ns][m]
// m97-faithful: 128M x 128N x 32K, 4 waves (2M x 2N), wave tile 64x64,
// acc[4][4] (AGPR). LDS 32 KB (A dbuf 2x8K + B dbuf 2x8K) + VGPR<=128
// (__launch_bounds__(256,4)) -> 16 waves/CU = 4 INDEPENDENT blocks/CU:
// other blocks' MFMA covers each block's barrier drain (m114/m97 mechanism).
// Plain __syncthreads(), ONE barrier/iter, no inline asm, no setprio —
// the compiler's own counted lgkmcnt + drain-at-barrier is the m97-proven
// schedule. Grid 784 = 196 panels x 4 slices, XCD-swizzled (panel's 4
// twins share an XCD -> A-panel L2 reuse, r8-proven).
// ---------------------------------------------------------------------------
__global__ __launch_bounds__(256, 4) void gemm_att(const float* __restrict__ enc,
                                                   const unsigned short* __restrict__ WTp,
                                                   const float* __restrict__ bias,
                                                   const float* __restrict__ Wfull,
                                                   float* __restrict__ att_part) {
    __shared__ __align__(16) char ldsA[2][8192];
    __shared__ __align__(16) char ldsB[2][8192];

    const int tid  = threadIdx.x;
    const int lane = tid & 63;
    const int wid  = tid >> 6;          // 0..3
    const int wm   = wid >> 1;          // 0..1 (M half: 64 rows)
    const int wn   = wid & 1;           // 0..1 (N half: 64 cols)
    const int cif  = lane & 15;
    const int rgrp = lane >> 4;

    // XCD swizzle (bijective for 784 = 24*32 + 16): panel g's 4 ns-twins
    // are 8 raw slots apart -> same XCD.
    const int raw = blockIdx.x;
    int g, ns;
    if (raw < 768) { g = (raw >> 5) * 8 + (raw & 7); ns = (raw >> 3) & 3; }
    else           { int r2 = raw - 768; g = 192 + (r2 >> 2); ns = r2 & 3; }
    const int m0 = g * BM;

    // A: thread t -> row r=t>>1, k-half h=t&1 (16 floats of the 32-K tile).
    const int r = tid >> 1, h = tid & 1;
    const float* pA = enc + (size_t)(m0 + r) * EDIM + h * 16;
    // two ds_write_b128 at chunk (r>>4), lane-slots h*32+(r&15), +16:
    const unsigned aWoff = (unsigned)((r >> 4) * 1024 + (h * 32 + (r & 15)) * 16);

    // B: wave wid copies image chunks wid*2, wid*2+1 (1 KB each).
    const unsigned short* pB = WTp + (size_t)ns * 4096 + (size_t)(wid * 2) * 512
                             + (size_t)lane * 8;            // + kt*16384
    const unsigned bgOff = (unsigned)(wid * 2048);

    char* aR = ldsA[0]; char* aW = ldsA[1];
    char* bR = ldsB[0]; char* bW = ldsB[1];

    f32x4 acc[4][4] = {};

    // ---- prologue: stage tile 0 into aR/bR ----
    GLOAD16(pB,       bR + bgOff);
    GLOAD16(pB + 512, bR + bgOff + 1024);
    {
        float4 t0 = *(const float4*)pA;
        float4 t1 = *(const float4*)(pA + 4);
        float4 t2 = *(const float4*)(pA + 8);
        float4 t3 = *(const float4*)(pA + 12);
        *(short8*)(aR + aWoff)       = cvt8(t0, t1);
        *(short8*)(aR + aWoff + 256) = cvt8(t2, t3);
    }
    __syncthreads();

    // ---- main loop: kt = 0 .. NK-2: stage kt+1, compute kt, 1 barrier ----
    for (int kt = 0; kt < NK - 1; ++kt) {
        // stage B(kt+1)
        const unsigned short* pb = pB + (size_t)(kt + 1) * 16384;
        GLOAD16(pb,       bW + bgOff);
        GLOAD16(pb + 512, bW + bgOff + 1024);
        // stage A(kt+1): global->reg->cvt->ds_write (to the write buffer)
        {
            const float* pa = pA + (kt + 1) * BK;
            float4 t0 = *(const float4*)pa;
            float4 t1 = *(const float4*)(pa + 4);
            float4 t2 = *(const float4*)(pa + 8);
            float4 t3 = *(const float4*)(pa + 12);
            *(short8*)(aW + aWoff)       = cvt8(t0, t1);
            *(short8*)(aW + aWoff + 256) = cvt8(t2, t3);
        }
        // compute kt
        {
            short8 a[4], b[4];
            #pragma unroll
            for (int i = 0; i < 4; ++i)
                a[i] = *(const short8*)(aR + (wm * 4 + i) * 1024 + lane * 16);
            #pragma unroll
            for (int j = 0; j < 4; ++j)
                b[j] = *(const short8*)(bR + (wn * 4 + j) * 1024 + lane * 16);
            #pragma unroll
            for (int i = 0; i < 4; ++i)
                #pragma unroll
                for (int j = 0; j < 4; ++j)
                    acc[i][j] = MFMA16(a[i], b[j], acc[i][j]);
        }
        __syncthreads();
        { char* t = aR; aR = aW; aW = t; }
        { char* t = bR; bR = bW; bW = t; }
    }
    // ---- final compute kt = NK-1 ----
    {
        short8 a[4], b[4];
        #pragma unroll
        for (int i = 0; i < 4; ++i)
            a[i] = *(const short8*)(aR + (wm * 4 + i) * 1024 + lane * 16);
        #pragma unroll
        for (int j = 0; j < 4; ++j)
            b[j] = *(const short8*)(bR + (wn * 4 + j) * 1024 + lane * 16);
        #pragma unroll
        for (int i = 0; i < 4; ++i)
            #pragma unroll
            for (int j = 0; j < 4; ++j)
                acc[i][j] = MFMA16(a[i], b[j], acc[i][j]);
    }
    __syncthreads();   // before aliasing ldsA as reduction buffer

    // ---- epilogue: relu(acc + bias) . Wfull over this slice's 128 cols ----
    float* red = (float*)ldsA;   // [2][128] floats (aliases ldsA)
    const int bf  = m0 / PIX;
    const int thr = (bf + 1) * PIX;
    const int bfc = (bf + 1 < BATCH) ? bf + 1 : BATCH - 1;
    float wf[4], bs0[4], bs1[4];
    #pragma unroll
    for (int j = 0; j < 4; ++j) {
        int aj = ns * 128 + wn * 64 + j * 16 + cif;
        wf[j]  = Wfull[aj];
        bs0[j] = bias[(size_t)bf  * ADIM + aj];
        bs1[j] = bias[(size_t)bfc * ADIM + aj];
    }
    #pragma unroll
    for (int i = 0; i < 4; ++i) {
        #pragma unroll
        for (int rr = 0; rr < 4; ++rr) {
            int ml = wm * 64 + i * 16 + rgrp * 4 + rr;
            int m  = m0 + ml;
            bool sec = (m >= thr);
            float s = 0.f;
            #pragma unroll
            for (int j = 0; j < 4; ++j) {
                float v = acc[i][j][rr] + (sec ? bs1[j] : bs0[j]);
                s += fmaxf(v, 0.f) * wf[j];
            }
            s += __shfl_xor(s, 1);
            s += __shfl_xor(s, 2);
            s += __shfl_xor(s, 4);
            s += __shfl_xor(s, 8);
            if (cif == 0) red[wn * 128 + ml] = s;
        }
    }
    __syncthreads();
    if (tid < BM)
        att_part[(size_t)ns * MTOT + m0 + tid] = red[tid] + red[128 + tid];
}

// ---------------------------------------------------------------------------
// Kernel 3: softmax over p; att = sum of 4 N-slice partials (b_full cancels)
// ---------------------------------------------------------------------------
__global__ __launch_bounds__(256) void softmax_kernel(const float* __restrict__ att_part,
                                                      float* __restrict__ alpha) {
    const int b = blockIdx.x;
    const int tid = threadIdx.x;
    const int lane = tid & 63, wid = tid >> 6;
    __shared__ float wred[4];

    float x = -1e30f;
    if (tid < PIX) {
        size_t m = (size_t)b * PIX + tid;
        x = att_part[m] + att_part[MTOT + m] + att_part[2 * MTOT + m]
          + att_part[3 * MTOT + m];
    }
    float mx = x;
    #pragma unroll
    for (int off = 32; off >= 1; off >>= 1) mx = fmaxf(mx, __shfl_xor(mx, off));
    if (lane == 0) wred[wid] = mx;
    __syncthreads();
    float gm = fmaxf(fmaxf(wred[0], wred[1]), fmaxf(wred[2], wred[3]));
    __syncthreads();

    float e = (tid < PIX) ? __expf(x - gm) : 0.f;
    float s = e;
    #pragma unroll
    for (int off = 32; off >= 1; off >>= 1) s += __shfl_xor(s, off);
    if (lane == 0) wred[wid] = s;
    __syncthreads();
    float gs = wred[0] + wred[1] + wred[2] + wred[3];

    if (tid < PIX) alpha[(size_t)b * PIX + tid] = e / gs;
}

// ---------------------------------------------------------------------------
// Kernel 4: out[b][e] = sum_p enc[b][p][e] * alpha[b][p]
// ---------------------------------------------------------------------------
__global__ __launch_bounds__(128) void weighted_kernel(const float* __restrict__ enc,
                                                       const float* __restrict__ alpha,
                                                       float* __restrict__ out) {
    const int b = blockIdx.x >> 2;
    const int q = blockIdx.x & 3;
    const int tid = threadIdx.x;
    __shared__ float al[PIX];
    for (int i = tid; i < PIX; i += 128) al[i] = alpha[(size_t)b * PIX + i];
    __syncthreads();

    const int e = q * 512 + tid * 4;
    const float4* src = (const float4*)(enc + (size_t)b * PIX * EDIM + e);
    float ax = 0.f, ay = 0.f, az = 0.f, aw = 0.f;
    #pragma unroll 4
    for (int p = 0; p < PIX; p++) {
        float av = al[p];
        float4 v = src[(size_t)p * (EDIM / 4)];
        ax += av * v.x; ay += av * v.y; az += av * v.z; aw += av * v.w;
    }
    float4 o; o.x = ax; o.y = ay; o.z = az; o.w = aw;
    *(float4*)&out[(size_t)b * EDIM + e] = o;
}

// ---------------------------------------------------------------------------
extern "C" void kernel_launch(void* const* d_in, const int* in_sizes, int n_in,
                              void* d_out, int out_size, void* d_ws, size_t ws_size,
                              hipStream_t stream) {
    const float* enc   = (const float*)d_in[0];   // [128,196,2048]
    const float* dec   = (const float*)d_in[1];   // [128,512]
    const float* Wenc  = (const float*)d_in[2];   // [2048,512]
    const float* benc  = (const float*)d_in[3];   // [512]
    const float* Wdec  = (const float*)d_in[4];   // [512,512]
    const float* bdec  = (const float*)d_in[5];   // [512]
    const float* Wfull = (const float*)d_in[6];   // [512]
    // d_in[7] = b_full: constant shift, cancels in softmax

    float* out_awe   = (float*)d_out;                       // [128,2048]
    float* out_alpha = (float*)d_out + BATCH * EDIM;        // [128,196]

    char* ws = (char*)d_ws;
    unsigned short* WTp = (unsigned short*)ws;                      // 2 MB packed images
    float* bias = (float*)(ws + (size_t)ADIM * EDIM * 2);           // 256 KB [128][512]
    float* att_part = (float*)(ws + (size_t)ADIM * EDIM * 2
                             + (size_t)BATCH * ADIM * 4);           // 4 x 100 KB

    pack_wenc<<<NK, 256, 0, stream>>>(Wenc, WTp);
    bias_kernel<<<BATCH / 4, 256, 0, stream>>>(dec, Wdec, benc, bdec, bias);
    gemm_att<<<(MTOT / BM) * NSLC, 256, 0, stream>>>(enc, WTp, bias, Wfull, att_part);
    softmax_kernel<<<BATCH, 256, 0, stream>>>(att_part, out_alpha);
    weighted_kernel<<<BATCH * 4, 128, 0, stream>>>(enc, out_alpha, out_awe);
}